// Round 5
// baseline (796.226 us; speedup 1.0000x reference)
//
#include <hip/hip_runtime.h>
#include <hip/hip_bf16.h>
#include <cstdint>
#include <cstddef>

// Problem dims
#define B_   128
#define L_   1024
#define H_   256
#define E_   128
#define V_   50000
#define X_   100
#define VX_  50100      // V + X
#define LSTR 50112      // padded row stride for bf16 logits buffer

// d_out offsets (elements), tuple return order:
// final_dist[B,VX], h[B,H], c[B,H], c_t[B,2H], a[B,L], p_gen[B,1], coverage_next[B,L]
#define OUT_H    6412800
#define OUT_C    6445568
#define OUT_CT   6478336
#define OUT_A    6543872
#define OUT_PGEN 6674944
#define OUT_COV  6675072

typedef __attribute__((ext_vector_type(8))) short bf16x8;           // MFMA A/B frag (8 bf16 = 4 VGPR)
typedef __attribute__((ext_vector_type(4))) float f32x4;            // MFMA C/D frag
typedef __attribute__((ext_vector_type(8))) unsigned short u16x8;   // 16B bf16 vector load

__device__ inline float bf2f(unsigned short u){
  union { unsigned int i; float f; } v; v.i = ((unsigned int)u) << 16; return v.f;
}
__device__ inline unsigned short f2bf(float f){   // round-to-nearest-even
  union { float f; unsigned int i; } v; v.f = f;
  unsigned int lsb = (v.i >> 16) & 1u;
  v.i += 0x7fffu + lsb;
  return (unsigned short)(v.i >> 16);
}
__device__ inline float sigm(float x){ return __builtin_amdgcn_rcpf(1.f + __expf(-x)); }
__device__ inline float tanh_f(float x){          // overflow-safe fast tanh
  float ax = fabsf(x);
  float t  = __expf(-2.f * ax);
  float r  = (1.f - t) * __builtin_amdgcn_rcpf(1.f + t);
  return copysignf(r, x);
}
// dtype probe: enc_padding_mask is all-ones. bf16 1.0 -> halfword0 = 0x3F80;
// f32 1.0 -> halfword0 = 0x0000. So f32 iff halfword0 != 0x3F80.
__device__ inline bool is_f32m(const void* mask){
  return ((const unsigned short*)mask)[0] != 0x3F80u;
}
__device__ inline float ldf(const void* p, size_t i, bool f32){
  return f32 ? ((const float*)p)[i] : bf2f(((const unsigned short*)p)[i]);
}
__device__ inline void stf(void* p, size_t i, float v, bool f32){
  if (f32) ((float*)p)[i] = v; else ((unsigned short*)p)[i] = f2bf(v);
}
__device__ inline void atomic_add_bf16(unsigned short* addr, float val){
  uintptr_t a = (uintptr_t)addr;
  unsigned int* word = (unsigned int*)(a & ~(uintptr_t)3);
  bool hi = (a & 2) != 0;
  unsigned int old = *word, assumed;
  do {
    assumed = old;
    unsigned short cur = hi ? (unsigned short)(assumed >> 16) : (unsigned short)(assumed & 0xffffu);
    unsigned short nv = f2bf(bf2f(cur) + val);
    unsigned int next = hi ? ((assumed & 0x0000ffffu) | ((unsigned int)nv << 16))
                           : ((assumed & 0xffff0000u) | (unsigned int)nv);
    old = atomicCAS(word, assumed, next);
  } while (old != assumed);
}

// k_pre: transpose small weight matrices into f32 workspace copies so the
// GEMV kernels get lane-coalesced weight reads. Also merges LSTM biases.
__global__ void k_pre(const void* __restrict__ xctx_W, const void* __restrict__ Wih,
                      const void* __restrict__ Whh, const void* __restrict__ Ws_W,
                      const void* __restrict__ proj_W, const void* __restrict__ bih,
                      const void* __restrict__ bhh, const void* __restrict__ mask,
                      float* __restrict__ xctxT, float* __restrict__ gatesT,
                      float* __restrict__ bg, float* __restrict__ WsT,
                      float* __restrict__ projT){
  bool f32 = is_f32m(mask);
  const int total = 81920 + 131072 + 262144 + 262144 + 196608 + 1024;  // 934912
  for (int e = blockIdx.x * 256 + threadIdx.x; e < total; e += gridDim.x * 256){
    int r = e;
    if (r < 81920){
      int n = r / 640, k = r - n * 640;
      xctxT[k * 128 + n] = ldf(xctx_W, r, f32);
    } else if ((r -= 81920) < 131072){
      int n = r >> 7, k = r & 127;
      gatesT[k * 1024 + n] = ldf(Wih, r, f32);
    } else if ((r -= 131072) < 262144){
      int n = r >> 8, k = r & 255;
      gatesT[(128 + k) * 1024 + n] = ldf(Whh, r, f32);
    } else if ((r -= 262144) < 262144){
      int n = r >> 9, k = r & 511;
      WsT[k * 512 + n] = ldf(Ws_W, r, f32);
    } else if ((r -= 262144) < 196608){
      int n = r / 768, k = r - n * 768;
      projT[k * 256 + n] = ldf(proj_W, r, f32);
    } else {
      r -= 196608;
      bg[r] = ldf(bih, r, f32) + ldf(bhh, r, f32);
    }
  }
}

// kA: fused k1+k2+k3 (x -> LSTM -> dec_feats), all row-local. One block per m.
__global__ void kA_row(const int* __restrict__ y_t, const void* __restrict__ c_t_1,
                       const void* __restrict__ embed_W, const void* __restrict__ h0,
                       const void* __restrict__ c0, const float* __restrict__ xctxT,
                       const void* __restrict__ xctx_b, const float* __restrict__ gatesT,
                       const float* __restrict__ bg, const float* __restrict__ WsT,
                       const void* __restrict__ Ws_b, const void* __restrict__ mask,
                       float* __restrict__ x_ws, float* __restrict__ st_ws,
                       float* __restrict__ dec_ws, void* __restrict__ out){
  bool f32 = is_f32m(mask);
  __shared__ float act[768];
  int m = blockIdx.x, t = threadIdx.x;   // 256 threads
  // --- P1: x = concat(c_t_1, emb) @ xctx_W.T + b ---
  act[t]       = ldf(c_t_1, (size_t)m * 512 + t, f32);
  act[256 + t] = ldf(c_t_1, (size_t)m * 512 + 256 + t, f32);
  if (t < 128){
    size_t em = (size_t)y_t[m] * 128;
    act[512 + t] = ldf(embed_W, em + t, f32);
  }
  __syncthreads();
  float xv = 0.f;
  if (t < 128){
    xv = ldf(xctx_b, t, f32);
    for (int k = 0; k < 640; ++k) xv += act[k] * xctxT[k * 128 + t];
  }
  __syncthreads();
  // --- P2: LSTM ---
  if (t < 128){ act[t] = xv; x_ws[m * 128 + t] = xv; }
  act[128 + t] = ldf(h0, (size_t)m * 256 + t, f32);
  __syncthreads();
  float g[4];
  #pragma unroll
  for (int gi = 0; gi < 4; ++gi) g[gi] = bg[t + gi * 256];
  for (int k = 0; k < 384; ++k){
    float a = act[k];
    const float* wr = gatesT + (size_t)k * 1024 + t;
    #pragma unroll
    for (int gi = 0; gi < 4; ++gi) g[gi] += a * wr[gi * 256];
  }
  float c0v = ldf(c0, (size_t)m * 256 + t, f32);
  float c = sigm(g[1]) * c0v + sigm(g[0]) * tanh_f(g[2]);
  float h = sigm(g[3]) * tanh_f(c);
  st_ws[m * 512 + t]       = h;
  st_ws[m * 512 + 256 + t] = c;
  stf(out, (size_t)OUT_H + m * 256 + t, h, f32);
  stf(out, (size_t)OUT_C + m * 256 + t, c, f32);
  // --- P3: dec_feats ---
  __syncthreads();
  act[t] = h; act[256 + t] = c;
  __syncthreads();
  float a0 = ldf(Ws_b, t, f32), a1 = ldf(Ws_b, t + 256, f32);
  for (int k = 0; k < 512; ++k){
    float a = act[k];
    const float* wr = WsT + (size_t)k * 512 + t;
    a0 += a * wr[0];
    a1 += a * wr[256];
  }
  dec_ws[m * 512 + t]       = a0;
  dec_ws[m * 512 + 256 + t] = a1;
}

// k4: energy[b,l] = sum_d v[d]*tanh(enc_feats + dec_feats + cov*Wc). One wave per (b,l).
__global__ void k4_energy(const void* __restrict__ enc_feats, const float* __restrict__ dec_ws,
                          const void* __restrict__ coverage, const void* __restrict__ Wc,
                          const void* __restrict__ vW, const void* __restrict__ mask,
                          float* __restrict__ energy_ws){
  bool f32 = is_f32m(mask);
  int g = blockIdx.x * 4 + (threadIdx.x >> 6);    // (b,l) id, 131072 waves
  int lane = threadIdx.x & 63;
  int b = g >> 10;
  int d0 = lane * 8;
  float vv[8], wc[8], ef[8];
  if (f32){
    const float* vp = (const float*)vW + d0;
    const float* wp = (const float*)Wc + d0;
    const float* ep = (const float*)enc_feats + (size_t)g * 512 + d0;
    float4 a0 = ((const float4*)vp)[0], a1 = ((const float4*)vp)[1];
    float4 b0 = ((const float4*)wp)[0], b1 = ((const float4*)wp)[1];
    float4 c0 = ((const float4*)ep)[0], c1 = ((const float4*)ep)[1];
    vv[0]=a0.x; vv[1]=a0.y; vv[2]=a0.z; vv[3]=a0.w; vv[4]=a1.x; vv[5]=a1.y; vv[6]=a1.z; vv[7]=a1.w;
    wc[0]=b0.x; wc[1]=b0.y; wc[2]=b0.z; wc[3]=b0.w; wc[4]=b1.x; wc[5]=b1.y; wc[6]=b1.z; wc[7]=b1.w;
    ef[0]=c0.x; ef[1]=c0.y; ef[2]=c0.z; ef[3]=c0.w; ef[4]=c1.x; ef[5]=c1.y; ef[6]=c1.z; ef[7]=c1.w;
  } else {
    u16x8 a = *(const u16x8*)((const unsigned short*)vW + d0);
    u16x8 w = *(const u16x8*)((const unsigned short*)Wc + d0);
    u16x8 e = *(const u16x8*)((const unsigned short*)enc_feats + (size_t)g * 512 + d0);
    #pragma unroll
    for (int jj = 0; jj < 8; ++jj){ vv[jj] = bf2f(a[jj]); wc[jj] = bf2f(w[jj]); ef[jj] = bf2f(e[jj]); }
  }
  const float4* dr = (const float4*)(dec_ws + b * 512 + d0);
  float4 dv0 = dr[0], dv1 = dr[1];
  float dec[8] = {dv0.x, dv0.y, dv0.z, dv0.w, dv1.x, dv1.y, dv1.z, dv1.w};
  float cov = ldf(coverage, g, f32);
  float acc = 0.f;
  #pragma unroll
  for (int jj = 0; jj < 8; ++jj){
    float f = ef[jj] + dec[jj] + cov * wc[jj];
    acc += tanh_f(f) * vv[jj];
  }
  #pragma unroll
  for (int off = 32; off > 0; off >>= 1) acc += __shfl_down(acc, off, 64);
  if (lane == 0) energy_ws[g] = acc;
}

// k5: masked softmax over L with renorm; write a (f32 ws + out), coverage_next (out), zero ct accum.
__global__ void k5_attn(const float* __restrict__ energy_ws, const void* __restrict__ mask,
                        const void* __restrict__ coverage,
                        float* __restrict__ a_ws, float* __restrict__ ct_ws, void* __restrict__ out){
  bool f32 = is_f32m(mask);
  __shared__ float red[256];
  int b = blockIdx.x, t = threadIdx.x;
  const float* er = energy_ws + b * 1024;
  float e[4];
  float mx = -1e30f;
  #pragma unroll
  for (int i = 0; i < 4; ++i){ e[i] = er[t + i * 256]; mx = fmaxf(mx, e[i]); }
  red[t] = mx; __syncthreads();
  for (int s = 128; s > 0; s >>= 1){ if (t < s) red[t] = fmaxf(red[t], red[t + s]); __syncthreads(); }
  float M = red[0]; __syncthreads();
  float sum = 0.f;
  #pragma unroll
  for (int i = 0; i < 4; ++i){
    float mk = ldf(mask, (size_t)b * 1024 + t + i * 256, f32);
    e[i] = __expf(e[i] - M) * mk;
    sum += e[i];
  }
  red[t] = sum; __syncthreads();
  for (int s = 128; s > 0; s >>= 1){ if (t < s) red[t] += red[t + s]; __syncthreads(); }
  float inv = 1.f / red[0];
  #pragma unroll
  for (int i = 0; i < 4; ++i){
    int l = t + i * 256;
    float av = e[i] * inv;
    a_ws[b * 1024 + l] = av;
    stf(out, (size_t)OUT_A + b * 1024 + l, av, f32);
    stf(out, (size_t)OUT_COV + b * 1024 + l, ldf(coverage, (size_t)b * 1024 + l, f32) + av, f32);
  }
  ct_ws[b * 512 + t] = 0.f;           // zero c_t accumulator for k6 atomics
  ct_ws[b * 512 + t + 256] = 0.f;
}

// k6: c_t[b,d] = sum_l a[b,l]*enc_outs[b,l,d]. 4 blocks per b, 2 d's per thread, f32 atomics.
__global__ void k6_ctx(const float* __restrict__ a_ws, const void* __restrict__ enc_outs,
                       const void* __restrict__ mask, float* __restrict__ ct_ws){
  bool f32 = is_f32m(mask);
  __shared__ float ash[256];
  int blk = blockIdx.x;
  int b = blk >> 2, part = blk & 3;
  int t = threadIdx.x;                 // 256 threads
  int l0 = part * 256;
  ash[t] = a_ws[b * 1024 + l0 + t];
  __syncthreads();
  int d = t * 2;
  float acc0 = 0.f, acc1 = 0.f;
  if (f32){
    const float* base = (const float*)enc_outs + ((size_t)(b * 1024 + l0)) * 512 + d;
    for (int l = 0; l < 256; ++l){
      float2 v = *(const float2*)(base + (size_t)l * 512);
      float a = ash[l];
      acc0 += a * v.x; acc1 += a * v.y;
    }
  } else {
    const unsigned short* base = (const unsigned short*)enc_outs + ((size_t)(b * 1024 + l0)) * 512 + d;
    for (int l = 0; l < 256; ++l){
      unsigned int pk = *(const unsigned int*)(base + (size_t)l * 512);
      float a = ash[l];
      acc0 += a * bf2f((unsigned short)(pk & 0xffffu));
      acc1 += a * bf2f((unsigned short)(pk >> 16));
    }
  }
  atomicAdd(&ct_ws[b * 512 + d],     acc0);
  atomicAdd(&ct_ws[b * 512 + d + 1], acc1);
}

// kC: fused k7+k8 (pgen + c_t out + out_hid), row-local after ct complete.
__global__ void kC_row(const float* __restrict__ ct_ws, const float* __restrict__ st_ws,
                       const float* __restrict__ x_ws, const void* __restrict__ pgen_W,
                       const void* __restrict__ pgen_b, const float* __restrict__ projT,
                       const void* __restrict__ proj_b, const void* __restrict__ mask,
                       float* __restrict__ pgen_ws, unsigned short* __restrict__ outhid_bf,
                       void* __restrict__ out){
  bool f32 = is_f32m(mask);
  __shared__ float act[768];
  int b = blockIdx.x, t = threadIdx.x;
  // --- P7: pgen ---
  stf(out, (size_t)OUT_CT + b * 512 + t,       ct_ws[b * 512 + t], f32);
  stf(out, (size_t)OUT_CT + b * 512 + t + 256, ct_ws[b * 512 + t + 256], f32);
  float acc = 0.f;
  for (int k = t; k < 1152; k += 256){
    float v = (k < 512) ? ct_ws[b * 512 + k]
            : (k < 1024) ? st_ws[b * 512 + (k - 512)]
            : x_ws[b * 128 + (k - 1024)];
    acc += v * ldf(pgen_W, k, f32);
  }
  act[t] = acc; __syncthreads();
  for (int s = 128; s > 0; s >>= 1){ if (t < s) act[t] += act[t + s]; __syncthreads(); }
  if (t == 0){
    float p = sigm(act[0] + ldf(pgen_b, 0, f32));
    pgen_ws[b] = p;
    stf(out, (size_t)OUT_PGEN + b, p, f32);
  }
  __syncthreads();
  // --- P8: out_hid ---
  act[t]       = st_ws[b * 512 + t];          // h
  act[256 + t] = ct_ws[b * 512 + t];
  act[512 + t] = ct_ws[b * 512 + 256 + t];
  __syncthreads();
  float oacc = ldf(proj_b, t, f32);
  for (int k = 0; k < 768; ++k) oacc += act[k] * projT[k * 256 + t];
  outhid_bf[b * 256 + t] = f2bf(oacc);
}

// k9: logits = out_hid[128,256] @ out_W.T + out_b via bf16 MFMA 16x16x32.
__global__ void k9_logits(const unsigned short* __restrict__ outhid_bf, const void* __restrict__ out_W,
                          const void* __restrict__ out_b, const void* __restrict__ mask,
                          unsigned short* __restrict__ logits_bf){
  bool f32 = is_f32m(mask);
  int wid = blockIdx.x * 4 + (threadIdx.x >> 6);
  if (wid >= V_ / 16) return;
  int lane = threadIdx.x & 63;
  int q = lane >> 4, r = lane & 15;
  int n0 = wid * 16;
  const bf16x8* Ar = (const bf16x8*)(outhid_bf);
  float bias = ldf(out_b, n0 + r, f32);
  f32x4 acc[8];
  #pragma unroll
  for (int mt = 0; mt < 8; ++mt) acc[mt] = (f32x4){0.f, 0.f, 0.f, 0.f};
  #pragma unroll
  for (int kk = 0; kk < 8; ++kk){                 // k0 = kk*32
    bf16x8 bfrag;
    if (f32){
      const float* wf = (const float*)out_W + (size_t)(n0 + r) * 256 + kk * 32 + q * 8;
      float4 w0 = ((const float4*)wf)[0], w1 = ((const float4*)wf)[1];
      bfrag[0] = (short)f2bf(w0.x); bfrag[1] = (short)f2bf(w0.y);
      bfrag[2] = (short)f2bf(w0.z); bfrag[3] = (short)f2bf(w0.w);
      bfrag[4] = (short)f2bf(w1.x); bfrag[5] = (short)f2bf(w1.y);
      bfrag[6] = (short)f2bf(w1.z); bfrag[7] = (short)f2bf(w1.w);
    } else {
      bfrag = ((const bf16x8*)((const unsigned short*)out_W + (size_t)(n0 + r) * 256))[kk * 4 + q];
    }
    #pragma unroll
    for (int mt = 0; mt < 8; ++mt){
      bf16x8 afrag = Ar[(mt * 16 + r) * 32 + kk * 4 + q];   // A[m=lane&15][k=q*8+j]
      acc[mt] = __builtin_amdgcn_mfma_f32_16x16x32_bf16(afrag, bfrag, acc[mt], 0, 0, 0);
    }
  }
  #pragma unroll
  for (int mt = 0; mt < 8; ++mt){
    #pragma unroll
    for (int rr = 0; rr < 4; ++rr){
      int m = mt * 16 + q * 4 + rr;               // D: col=lane&15, row=quad*4+reg
      logits_bf[(size_t)m * LSTR + n0 + r] = f2bf(acc[mt][rr] + bias);
    }
  }
}

// k10: per-(row, quarter) max + sumexp partials over bf16 logits
__global__ void k10_rowred(const unsigned short* __restrict__ logits_bf, float* __restrict__ pm, float* __restrict__ ps){
  __shared__ float red[256];
  int blk = blockIdx.x;        // b*4 + part
  int b = blk >> 2, part = blk & 3;
  int t = threadIdx.x;
  const unsigned short* row = logits_bf + (size_t)b * LSTR + part * 12500;
  float mx = -1e30f;
  for (int c = t; c < 12500; c += 256) mx = fmaxf(mx, bf2f(row[c]));
  red[t] = mx; __syncthreads();
  for (int s = 128; s > 0; s >>= 1){ if (t < s) red[t] = fmaxf(red[t], red[t + s]); __syncthreads(); }
  float M = red[0]; __syncthreads();
  float sum = 0.f;
  for (int c = t; c < 12500; c += 256) sum += __expf(bf2f(row[c]) - M);
  red[t] = sum; __syncthreads();
  for (int s = 128; s > 0; s >>= 1){ if (t < s) red[t] += red[t + s]; __syncthreads(); }
  if (t == 0){ pm[blk] = M; ps[blk] = red[0]; }
}

// k11s: merged k11+k12. One block per batch row b: write p_gen*softmax row into
// final_dist (plus zeros for the extended region), sync, then do this row's
// pointer-scatter atomics. Scatter targets are row-local so no cross-block order needed.
__global__ void k11s_vocab_scatter(const unsigned short* __restrict__ logits_bf,
                                   const float* __restrict__ pm, const float* __restrict__ ps,
                                   const float* __restrict__ pgen_ws, const float* __restrict__ a_ws,
                                   const int* __restrict__ ebev, const void* __restrict__ mask,
                                   void* __restrict__ out){
  bool f32 = is_f32m(mask);
  int b = blockIdx.x, t = threadIdx.x;   // 128 blocks x 256 threads
  float M = fmaxf(fmaxf(pm[b * 4], pm[b * 4 + 1]), fmaxf(pm[b * 4 + 2], pm[b * 4 + 3]));
  float S = 0.f;
  #pragma unroll
  for (int p = 0; p < 4; ++p) S += ps[b * 4 + p] * __expf(pm[b * 4 + p] - M);
  float pg = pgen_ws[b];
  float Sc = pg / S;
  const unsigned short* lrow = logits_bf + (size_t)b * LSTR;
  // vocab-dist row write (stride 2048 = 256 threads * 8 elems)
  for (int c0 = t * 8; c0 < VX_; c0 += 2048){
    #pragma unroll
    for (int j = 0; j < 8; ++j){
      int c = c0 + j;
      if (c < VX_){
        float v = (c < V_) ? __expf(bf2f(lrow[c]) - M) * Sc : 0.f;
        stf(out, (size_t)b * VX_ + c, v, f32);
      }
    }
  }
  __syncthreads();
  // pointer scatter for this row: 1024 entries, 4 per thread
  float q = 1.f - pg;
  #pragma unroll
  for (int i = 0; i < 4; ++i){
    int l = t + i * 256;
    int g = b * 1024 + l;
    float val = q * a_ws[g];
    size_t idx = (size_t)b * VX_ + ebev[g];
    if (f32) atomicAdd((float*)out + idx, val);
    else     atomic_add_bf16((unsigned short*)out + idx, val);
  }
}

extern "C" void kernel_launch(void* const* d_in, const int* in_sizes, int n_in,
                              void* d_out, int out_size, void* d_ws, size_t ws_size,
                              hipStream_t stream){
  const int*  y_t   = (const int*)d_in[0];
  const void* h0    = d_in[1];
  const void* c0    = d_in[2];
  const void* enc_outs  = d_in[3];
  const void* enc_feats = d_in[4];
  const void* mask  = d_in[5];
  const void* c_t_1 = d_in[6];
  // d_in[7] extra_zeros unused (zeros)
  const int*  ebev  = (const int*)d_in[8];
  const void* coverage = d_in[9];
  const void* embed_W = d_in[10];
  const void* Wih   = d_in[11];
  const void* Whh   = d_in[12];
  const void* bih   = d_in[13];
  const void* bhh   = d_in[14];
  const void* xctx_W = d_in[15];
  const void* xctx_b = d_in[16];
  const void* Ws_W  = d_in[17];
  const void* Ws_b  = d_in[18];
  const void* Wc_W  = d_in[19];
  const void* v_W   = d_in[20];
  const void* pgen_W = d_in[21];
  const void* pgen_b = d_in[22];
  const void* proj_W = d_in[23];
  const void* proj_b = d_in[24];
  const void* out_W = d_in[25];
  const void* out_b = d_in[26];

  // Workspace layout (float units). Total ~18.6 MB.
  float* ws        = (float*)d_ws;
  float* x_ws      = ws;                   // @0        16384
  float* st_ws     = ws + 16384;           //           65536
  float* dec_ws    = ws + 81920;           //           65536
  float* energy_ws = ws + 147456;          //           131072
  float* a_ws      = ws + 278528;          //           131072
  float* ct_ws     = ws + 409600;          //           65536
  float* pgen_ws   = ws + 475136;          //           128
  float* pm_ws     = ws + 475264;          //           512
  float* ps_ws     = ws + 475776;          //           512
  unsigned short* outhid_bf = (unsigned short*)(ws + 476576);  // 16384 floats (32768 bf16)
  unsigned short* logits_bf = (unsigned short*)(ws + 492960);  // 128*LSTR bf16 = 3207168 floats
  float* xctxT     = ws + 3700128;         //           81920
  float* gatesT    = ws + 3782048;         //           393216
  float* bg_ws     = ws + 4175264;         //           1024
  float* WsT       = ws + 4176288;         //           262144
  float* projT     = ws + 4438432;         //           196608  (end 4635040)

  k_pre  <<<1024, 256, 0, stream>>>(xctx_W, Wih, Whh, Ws_W, proj_W, bih, bhh, mask,
                                    xctxT, gatesT, bg_ws, WsT, projT);
  kA_row <<<128, 256, 0, stream>>>(y_t, c_t_1, embed_W, h0, c0, xctxT, xctx_b,
                                   gatesT, bg_ws, WsT, Ws_b, mask,
                                   x_ws, st_ws, dec_ws, d_out);
  k4_energy<<<32768, 256, 0, stream>>>(enc_feats, dec_ws, coverage, Wc_W, v_W, mask, energy_ws);
  k5_attn<<<128, 256, 0, stream>>>(energy_ws, mask, coverage, a_ws, ct_ws, d_out);
  k6_ctx <<<512, 256, 0, stream>>>(a_ws, enc_outs, mask, ct_ws);
  kC_row <<<128, 256, 0, stream>>>(ct_ws, st_ws, x_ws, pgen_W, pgen_b, projT, proj_b,
                                   mask, pgen_ws, outhid_bf, d_out);
  k9_logits<<<(V_ / 16 + 3) / 4, 256, 0, stream>>>(outhid_bf, out_W, out_b, mask, logits_bf);
  k10_rowred<<<512, 256, 0, stream>>>(logits_bf, pm_ws, ps_ws);
  k11s_vocab_scatter<<<128, 256, 0, stream>>>(logits_bf, pm_ws, ps_ws, pgen_ws, a_ws,
                                              ebev, mask, d_out);
}

// Round 6
// 765.301 us; speedup vs baseline: 1.0404x; 1.0404x over previous
//
#include <hip/hip_runtime.h>
#include <hip/hip_bf16.h>
#include <cstdint>
#include <cstddef>

// Problem dims
#define B_   128
#define L_   1024
#define H_   256
#define E_   128
#define V_   50000
#define X_   100
#define VX_  50100      // V + X
#define LSTR 50112      // padded row stride for bf16 logits buffer

// d_out offsets (elements), tuple return order:
// final_dist[B,VX], h[B,H], c[B,H], c_t[B,2H], a[B,L], p_gen[B,1], coverage_next[B,L]
#define OUT_H    6412800
#define OUT_C    6445568
#define OUT_CT   6478336
#define OUT_A    6543872
#define OUT_PGEN 6674944
#define OUT_COV  6675072

typedef __attribute__((ext_vector_type(8))) short bf16x8;           // MFMA A/B frag (8 bf16 = 4 VGPR)
typedef __attribute__((ext_vector_type(4))) float f32x4;            // MFMA C/D frag
typedef __attribute__((ext_vector_type(8))) unsigned short u16x8;   // 16B bf16 vector load
typedef __attribute__((ext_vector_type(4))) unsigned short u16x4;   // 8B bf16 vector store

__device__ inline float bf2f(unsigned short u){
  union { unsigned int i; float f; } v; v.i = ((unsigned int)u) << 16; return v.f;
}
__device__ inline unsigned short f2bf(float f){   // round-to-nearest-even
  union { float f; unsigned int i; } v; v.f = f;
  unsigned int lsb = (v.i >> 16) & 1u;
  v.i += 0x7fffu + lsb;
  return (unsigned short)(v.i >> 16);
}
__device__ inline float sigm(float x){ return __builtin_amdgcn_rcpf(1.f + __expf(-x)); }
__device__ inline float tanh_f(float x){          // overflow-safe fast tanh
  float ax = fabsf(x);
  float t  = __expf(-2.f * ax);
  float r  = (1.f - t) * __builtin_amdgcn_rcpf(1.f + t);
  return copysignf(r, x);
}
// dtype probe: enc_padding_mask is all-ones. bf16 1.0 -> halfword0 = 0x3F80;
// f32 1.0 -> halfword0 = 0x0000. So f32 iff halfword0 != 0x3F80.
__device__ inline bool is_f32m(const void* mask){
  return ((const unsigned short*)mask)[0] != 0x3F80u;
}
__device__ inline float ldf(const void* p, size_t i, bool f32){
  return f32 ? ((const float*)p)[i] : bf2f(((const unsigned short*)p)[i]);
}
__device__ inline void stf(void* p, size_t i, float v, bool f32){
  if (f32) ((float*)p)[i] = v; else ((unsigned short*)p)[i] = f2bf(v);
}
__device__ inline void atomic_add_bf16(unsigned short* addr, float val){
  uintptr_t a = (uintptr_t)addr;
  unsigned int* word = (unsigned int*)(a & ~(uintptr_t)3);
  bool hi = (a & 2) != 0;
  unsigned int old = *word, assumed;
  do {
    assumed = old;
    unsigned short cur = hi ? (unsigned short)(assumed >> 16) : (unsigned short)(assumed & 0xffffu);
    unsigned short nv = f2bf(bf2f(cur) + val);
    unsigned int next = hi ? ((assumed & 0x0000ffffu) | ((unsigned int)nv << 16))
                           : ((assumed & 0xffff0000u) | (unsigned int)nv);
    old = atomicCAS(word, assumed, next);
  } while (old != assumed);
}

// k_pre: transpose small weight matrices into f32 workspace copies so the
// GEMV kernels get lane-coalesced weight reads. Also merges LSTM biases.
__global__ void k_pre(const void* __restrict__ xctx_W, const void* __restrict__ Wih,
                      const void* __restrict__ Whh, const void* __restrict__ Ws_W,
                      const void* __restrict__ proj_W, const void* __restrict__ bih,
                      const void* __restrict__ bhh, const void* __restrict__ mask,
                      float* __restrict__ xctxT, float* __restrict__ gatesT,
                      float* __restrict__ bg, float* __restrict__ WsT,
                      float* __restrict__ projT){
  bool f32 = is_f32m(mask);
  const int total = 81920 + 131072 + 262144 + 262144 + 196608 + 1024;  // 934912
  for (int e = blockIdx.x * 256 + threadIdx.x; e < total; e += gridDim.x * 256){
    int r = e;
    if (r < 81920){
      int n = r / 640, k = r - n * 640;
      xctxT[k * 128 + n] = ldf(xctx_W, r, f32);
    } else if ((r -= 81920) < 131072){
      int n = r >> 7, k = r & 127;
      gatesT[k * 1024 + n] = ldf(Wih, r, f32);
    } else if ((r -= 131072) < 262144){
      int n = r >> 8, k = r & 255;
      gatesT[(128 + k) * 1024 + n] = ldf(Whh, r, f32);
    } else if ((r -= 262144) < 262144){
      int n = r >> 9, k = r & 511;
      WsT[k * 512 + n] = ldf(Ws_W, r, f32);
    } else if ((r -= 262144) < 196608){
      int n = r / 768, k = r - n * 768;
      projT[k * 256 + n] = ldf(proj_W, r, f32);
    } else {
      r -= 196608;
      bg[r] = ldf(bih, r, f32) + ldf(bhh, r, f32);
    }
  }
}

// kA: fused k1+k2+k3 (x -> LSTM -> dec_feats), all row-local. One block per m.
__global__ void kA_row(const int* __restrict__ y_t, const void* __restrict__ c_t_1,
                       const void* __restrict__ embed_W, const void* __restrict__ h0,
                       const void* __restrict__ c0, const float* __restrict__ xctxT,
                       const void* __restrict__ xctx_b, const float* __restrict__ gatesT,
                       const float* __restrict__ bg, const float* __restrict__ WsT,
                       const void* __restrict__ Ws_b, const void* __restrict__ mask,
                       float* __restrict__ x_ws, float* __restrict__ st_ws,
                       float* __restrict__ dec_ws, void* __restrict__ out){
  bool f32 = is_f32m(mask);
  __shared__ float act[768];
  int m = blockIdx.x, t = threadIdx.x;   // 256 threads
  // --- P1: x = concat(c_t_1, emb) @ xctx_W.T + b ---
  act[t]       = ldf(c_t_1, (size_t)m * 512 + t, f32);
  act[256 + t] = ldf(c_t_1, (size_t)m * 512 + 256 + t, f32);
  if (t < 128){
    size_t em = (size_t)y_t[m] * 128;
    act[512 + t] = ldf(embed_W, em + t, f32);
  }
  __syncthreads();
  float xv = 0.f;
  if (t < 128){
    xv = ldf(xctx_b, t, f32);
    for (int k = 0; k < 640; ++k) xv += act[k] * xctxT[k * 128 + t];
  }
  __syncthreads();
  // --- P2: LSTM ---
  if (t < 128){ act[t] = xv; x_ws[m * 128 + t] = xv; }
  act[128 + t] = ldf(h0, (size_t)m * 256 + t, f32);
  __syncthreads();
  float g[4];
  #pragma unroll
  for (int gi = 0; gi < 4; ++gi) g[gi] = bg[t + gi * 256];
  for (int k = 0; k < 384; ++k){
    float a = act[k];
    const float* wr = gatesT + (size_t)k * 1024 + t;
    #pragma unroll
    for (int gi = 0; gi < 4; ++gi) g[gi] += a * wr[gi * 256];
  }
  float c0v = ldf(c0, (size_t)m * 256 + t, f32);
  float c = sigm(g[1]) * c0v + sigm(g[0]) * tanh_f(g[2]);
  float h = sigm(g[3]) * tanh_f(c);
  st_ws[m * 512 + t]       = h;
  st_ws[m * 512 + 256 + t] = c;
  stf(out, (size_t)OUT_H + m * 256 + t, h, f32);
  stf(out, (size_t)OUT_C + m * 256 + t, c, f32);
  // --- P3: dec_feats ---
  __syncthreads();
  act[t] = h; act[256 + t] = c;
  __syncthreads();
  float a0 = ldf(Ws_b, t, f32), a1 = ldf(Ws_b, t + 256, f32);
  for (int k = 0; k < 512; ++k){
    float a = act[k];
    const float* wr = WsT + (size_t)k * 512 + t;
    a0 += a * wr[0];
    a1 += a * wr[256];
  }
  dec_ws[m * 512 + t]       = a0;
  dec_ws[m * 512 + 256 + t] = a1;
}

// k4: energy[b,l] = sum_d v[d]*tanh(enc_feats + dec_feats + cov*Wc).
// 1024 blocks x 4 waves; each wave loops 32 rows (amortizes vv/wc setup).
__global__ void k4_energy(const void* __restrict__ enc_feats, const float* __restrict__ dec_ws,
                          const void* __restrict__ coverage, const void* __restrict__ Wc,
                          const void* __restrict__ vW, const void* __restrict__ mask,
                          float* __restrict__ energy_ws){
  bool f32 = is_f32m(mask);
  int wave = blockIdx.x * 4 + (threadIdx.x >> 6);  // 4096 waves
  int lane = threadIdx.x & 63;
  int d0 = lane * 8;
  float vv[8], wc[8];
  if (f32){
    const float4* vp = (const float4*)((const float*)vW + d0);
    const float4* wp = (const float4*)((const float*)Wc + d0);
    float4 a0 = vp[0], a1 = vp[1], b0 = wp[0], b1 = wp[1];
    vv[0]=a0.x; vv[1]=a0.y; vv[2]=a0.z; vv[3]=a0.w; vv[4]=a1.x; vv[5]=a1.y; vv[6]=a1.z; vv[7]=a1.w;
    wc[0]=b0.x; wc[1]=b0.y; wc[2]=b0.z; wc[3]=b0.w; wc[4]=b1.x; wc[5]=b1.y; wc[6]=b1.z; wc[7]=b1.w;
  } else {
    u16x8 a = *(const u16x8*)((const unsigned short*)vW + d0);
    u16x8 w = *(const u16x8*)((const unsigned short*)Wc + d0);
    #pragma unroll
    for (int jj = 0; jj < 8; ++jj){ vv[jj] = bf2f(a[jj]); wc[jj] = bf2f(w[jj]); }
  }
  for (int i = 0; i < 32; ++i){
    int g = wave + 4096 * i;            // (b,l) id in [0,131072)
    int b = g >> 10;
    float ef[8];
    if (f32){
      const float4* ep = (const float4*)((const float*)enc_feats + (size_t)g * 512 + d0);
      float4 c0v = ep[0], c1v = ep[1];
      ef[0]=c0v.x; ef[1]=c0v.y; ef[2]=c0v.z; ef[3]=c0v.w; ef[4]=c1v.x; ef[5]=c1v.y; ef[6]=c1v.z; ef[7]=c1v.w;
    } else {
      u16x8 e = *(const u16x8*)((const unsigned short*)enc_feats + (size_t)g * 512 + d0);
      #pragma unroll
      for (int jj = 0; jj < 8; ++jj) ef[jj] = bf2f(e[jj]);
    }
    const float4* dr = (const float4*)(dec_ws + b * 512 + d0);
    float4 dv0 = dr[0], dv1 = dr[1];
    float dec[8] = {dv0.x, dv0.y, dv0.z, dv0.w, dv1.x, dv1.y, dv1.z, dv1.w};
    float cov = ldf(coverage, g, f32);
    float acc = 0.f;
    #pragma unroll
    for (int jj = 0; jj < 8; ++jj){
      float f = ef[jj] + dec[jj] + cov * wc[jj];
      acc += tanh_f(f) * vv[jj];
    }
    #pragma unroll
    for (int off = 32; off > 0; off >>= 1) acc += __shfl_down(acc, off, 64);
    if (lane == 0) energy_ws[g] = acc;
  }
}

// k5: masked softmax over L with renorm; write a (f32 ws + out), coverage_next (out), zero ct accum.
__global__ void k5_attn(const float* __restrict__ energy_ws, const void* __restrict__ mask,
                        const void* __restrict__ coverage,
                        float* __restrict__ a_ws, float* __restrict__ ct_ws, void* __restrict__ out){
  bool f32 = is_f32m(mask);
  __shared__ float red[256];
  int b = blockIdx.x, t = threadIdx.x;
  const float* er = energy_ws + b * 1024;
  float e[4];
  float mx = -1e30f;
  #pragma unroll
  for (int i = 0; i < 4; ++i){ e[i] = er[t + i * 256]; mx = fmaxf(mx, e[i]); }
  red[t] = mx; __syncthreads();
  for (int s = 128; s > 0; s >>= 1){ if (t < s) red[t] = fmaxf(red[t], red[t + s]); __syncthreads(); }
  float M = red[0]; __syncthreads();
  float sum = 0.f;
  #pragma unroll
  for (int i = 0; i < 4; ++i){
    float mk = ldf(mask, (size_t)b * 1024 + t + i * 256, f32);
    e[i] = __expf(e[i] - M) * mk;
    sum += e[i];
  }
  red[t] = sum; __syncthreads();
  for (int s = 128; s > 0; s >>= 1){ if (t < s) red[t] += red[t + s]; __syncthreads(); }
  float inv = 1.f / red[0];
  #pragma unroll
  for (int i = 0; i < 4; ++i){
    int l = t + i * 256;
    float av = e[i] * inv;
    a_ws[b * 1024 + l] = av;
    stf(out, (size_t)OUT_A + b * 1024 + l, av, f32);
    stf(out, (size_t)OUT_COV + b * 1024 + l, ldf(coverage, (size_t)b * 1024 + l, f32) + av, f32);
  }
  ct_ws[b * 512 + t] = 0.f;           // zero c_t accumulator for k6 atomics
  ct_ws[b * 512 + t + 256] = 0.f;
}

// k6: c_t[b,d] = sum_l a[b,l]*enc_outs[b,l,d]. 8 blocks per b (128 l each),
// 2 d's per thread, f32 atomics. 1024 blocks -> 4 waves/SIMD for latency hiding.
__global__ void k6_ctx(const float* __restrict__ a_ws, const void* __restrict__ enc_outs,
                       const void* __restrict__ mask, float* __restrict__ ct_ws){
  bool f32 = is_f32m(mask);
  __shared__ float ash[128];
  int blk = blockIdx.x;
  int b = blk >> 3, part = blk & 7;
  int t = threadIdx.x;                 // 256 threads
  int l0 = part * 128;
  if (t < 128) ash[t] = a_ws[b * 1024 + l0 + t];
  __syncthreads();
  int d = t * 2;
  float acc0 = 0.f, acc1 = 0.f;
  if (f32){
    const float* base = (const float*)enc_outs + ((size_t)(b * 1024 + l0)) * 512 + d;
    for (int l = 0; l < 128; ++l){
      float2 v = *(const float2*)(base + (size_t)l * 512);
      float a = ash[l];
      acc0 += a * v.x; acc1 += a * v.y;
    }
  } else {
    const unsigned short* base = (const unsigned short*)enc_outs + ((size_t)(b * 1024 + l0)) * 512 + d;
    for (int l = 0; l < 128; ++l){
      unsigned int pk = *(const unsigned int*)(base + (size_t)l * 512);
      float a = ash[l];
      acc0 += a * bf2f((unsigned short)(pk & 0xffffu));
      acc1 += a * bf2f((unsigned short)(pk >> 16));
    }
  }
  atomicAdd(&ct_ws[b * 512 + d],     acc0);
  atomicAdd(&ct_ws[b * 512 + d + 1], acc1);
}

// kC: fused k7+k8 (pgen + c_t out + out_hid), row-local after ct complete.
__global__ void kC_row(const float* __restrict__ ct_ws, const float* __restrict__ st_ws,
                       const float* __restrict__ x_ws, const void* __restrict__ pgen_W,
                       const void* __restrict__ pgen_b, const float* __restrict__ projT,
                       const void* __restrict__ proj_b, const void* __restrict__ mask,
                       float* __restrict__ pgen_ws, unsigned short* __restrict__ outhid_bf,
                       void* __restrict__ out){
  bool f32 = is_f32m(mask);
  __shared__ float act[768];
  int b = blockIdx.x, t = threadIdx.x;
  // --- P7: pgen ---
  stf(out, (size_t)OUT_CT + b * 512 + t,       ct_ws[b * 512 + t], f32);
  stf(out, (size_t)OUT_CT + b * 512 + t + 256, ct_ws[b * 512 + t + 256], f32);
  float acc = 0.f;
  for (int k = t; k < 1152; k += 256){
    float v = (k < 512) ? ct_ws[b * 512 + k]
            : (k < 1024) ? st_ws[b * 512 + (k - 512)]
            : x_ws[b * 128 + (k - 1024)];
    acc += v * ldf(pgen_W, k, f32);
  }
  act[t] = acc; __syncthreads();
  for (int s = 128; s > 0; s >>= 1){ if (t < s) act[t] += act[t + s]; __syncthreads(); }
  if (t == 0){
    float p = sigm(act[0] + ldf(pgen_b, 0, f32));
    pgen_ws[b] = p;
    stf(out, (size_t)OUT_PGEN + b, p, f32);
  }
  __syncthreads();
  // --- P8: out_hid ---
  act[t]       = st_ws[b * 512 + t];          // h
  act[256 + t] = ct_ws[b * 512 + t];
  act[512 + t] = ct_ws[b * 512 + 256 + t];
  __syncthreads();
  float oacc = ldf(proj_b, t, f32);
  for (int k = 0; k < 768; ++k) oacc += act[k] * projT[k * 256 + t];
  outhid_bf[b * 256 + t] = f2bf(oacc);
}

// k9: logits = out_hid[128,256] @ out_W.T + out_b via bf16 MFMA 16x16x32.
__global__ void k9_logits(const unsigned short* __restrict__ outhid_bf, const void* __restrict__ out_W,
                          const void* __restrict__ out_b, const void* __restrict__ mask,
                          unsigned short* __restrict__ logits_bf){
  bool f32 = is_f32m(mask);
  int wid = blockIdx.x * 4 + (threadIdx.x >> 6);
  if (wid >= V_ / 16) return;
  int lane = threadIdx.x & 63;
  int q = lane >> 4, r = lane & 15;
  int n0 = wid * 16;
  const bf16x8* Ar = (const bf16x8*)(outhid_bf);
  float bias = ldf(out_b, n0 + r, f32);
  f32x4 acc[8];
  #pragma unroll
  for (int mt = 0; mt < 8; ++mt) acc[mt] = (f32x4){0.f, 0.f, 0.f, 0.f};
  #pragma unroll
  for (int kk = 0; kk < 8; ++kk){                 // k0 = kk*32
    bf16x8 bfrag;
    if (f32){
      const float* wf = (const float*)out_W + (size_t)(n0 + r) * 256 + kk * 32 + q * 8;
      float4 w0 = ((const float4*)wf)[0], w1 = ((const float4*)wf)[1];
      bfrag[0] = (short)f2bf(w0.x); bfrag[1] = (short)f2bf(w0.y);
      bfrag[2] = (short)f2bf(w0.z); bfrag[3] = (short)f2bf(w0.w);
      bfrag[4] = (short)f2bf(w1.x); bfrag[5] = (short)f2bf(w1.y);
      bfrag[6] = (short)f2bf(w1.z); bfrag[7] = (short)f2bf(w1.w);
    } else {
      bfrag = ((const bf16x8*)((const unsigned short*)out_W + (size_t)(n0 + r) * 256))[kk * 4 + q];
    }
    #pragma unroll
    for (int mt = 0; mt < 8; ++mt){
      bf16x8 afrag = Ar[(mt * 16 + r) * 32 + kk * 4 + q];   // A[m=lane&15][k=q*8+j]
      acc[mt] = __builtin_amdgcn_mfma_f32_16x16x32_bf16(afrag, bfrag, acc[mt], 0, 0, 0);
    }
  }
  #pragma unroll
  for (int mt = 0; mt < 8; ++mt){
    #pragma unroll
    for (int rr = 0; rr < 4; ++rr){
      int m = mt * 16 + q * 4 + rr;               // D: col=lane&15, row=quad*4+reg
      logits_bf[(size_t)m * LSTR + n0 + r] = f2bf(acc[mt][rr] + bias);
    }
  }
}

// k10: per-(row, quarter) max + sumexp partials over bf16 logits
__global__ void k10_rowred(const unsigned short* __restrict__ logits_bf, float* __restrict__ pm, float* __restrict__ ps){
  __shared__ float red[256];
  int blk = blockIdx.x;        // b*4 + part
  int b = blk >> 2, part = blk & 3;
  int t = threadIdx.x;
  const unsigned short* row = logits_bf + (size_t)b * LSTR + part * 12500;
  float mx = -1e30f;
  for (int c = t; c < 12500; c += 256) mx = fmaxf(mx, bf2f(row[c]));
  red[t] = mx; __syncthreads();
  for (int s = 128; s > 0; s >>= 1){ if (t < s) red[t] = fmaxf(red[t], red[t + s]); __syncthreads(); }
  float M = red[0]; __syncthreads();
  float sum = 0.f;
  for (int c = t; c < 12500; c += 256) sum += __expf(bf2f(row[c]) - M);
  red[t] = sum; __syncthreads();
  for (int s = 128; s > 0; s >>= 1){ if (t < s) red[t] += red[t + s]; __syncthreads(); }
  if (t == 0){ pm[blk] = M; ps[blk] = red[0]; }
}

// k11: final[b,c] = p_gen * softmax(logits) for c<V, 0 for V<=c<VX. High-parallelism
// (3200 blocks), vectorized loads (u16x8) and stores (float4 / ushort4).
__global__ void k11_vocab(const unsigned short* __restrict__ logits_bf, const float* __restrict__ pm,
                          const float* __restrict__ ps, const float* __restrict__ pgen_ws,
                          const void* __restrict__ mask, void* __restrict__ out){
  bool f32 = is_f32m(mask);
  int b = blockIdx.y, t = threadIdx.x;
  float M = fmaxf(fmaxf(pm[b * 4], pm[b * 4 + 1]), fmaxf(pm[b * 4 + 2], pm[b * 4 + 3]));
  float S = 0.f;
  #pragma unroll
  for (int p = 0; p < 4; ++p) S += ps[b * 4 + p] * __expf(pm[b * 4 + p] - M);
  float Sc = pgen_ws[b] / S;
  int c0 = blockIdx.x * 2048 + t * 8;
  if (c0 >= VX_) return;
  const unsigned short* lrow = logits_bf + (size_t)b * LSTR;
  if (c0 + 8 <= V_){
    u16x8 lv = *(const u16x8*)(lrow + c0);
    float v[8];
    #pragma unroll
    for (int j = 0; j < 8; ++j) v[j] = __expf(bf2f(lv[j]) - M) * Sc;
    size_t idx = (size_t)b * VX_ + c0;     // idx % 4 == 0 (VX_ % 4 == 0, c0 % 8 == 0)
    if (f32){
      float4* o = (float4*)((float*)out + idx);
      o[0] = (float4){v[0], v[1], v[2], v[3]};
      o[1] = (float4){v[4], v[5], v[6], v[7]};
    } else {
      u16x4* o = (u16x4*)((unsigned short*)out + idx);
      u16x4 w0, w1;
      #pragma unroll
      for (int j = 0; j < 4; ++j){ w0[j] = f2bf(v[j]); w1[j] = f2bf(v[4 + j]); }
      o[0] = w0; o[1] = w1;
    }
  } else {
    #pragma unroll
    for (int j = 0; j < 8; ++j){
      int c = c0 + j;
      if (c < VX_){
        float v = (c < V_) ? __expf(bf2f(lrow[c]) - M) * Sc : 0.f;
        stf(out, (size_t)b * VX_ + c, v, f32);
      }
    }
  }
}

// k12: pointer scatter: final[b, ebev[b,l]] += (1-p_gen)*a[b,l], atomically on d_out.
__global__ void k12_scatter(const int* __restrict__ ebev, const float* __restrict__ a_ws,
                            const float* __restrict__ pgen_ws, const void* __restrict__ mask,
                            void* __restrict__ out){
  bool f32 = is_f32m(mask);
  int g = blockIdx.x * 256 + threadIdx.x;   // 131072
  int b = g >> 10;
  float val = (1.f - pgen_ws[b]) * a_ws[g];
  size_t idx = (size_t)b * VX_ + ebev[g];
  if (f32) atomicAdd((float*)out + idx, val);
  else     atomic_add_bf16((unsigned short*)out + idx, val);
}

extern "C" void kernel_launch(void* const* d_in, const int* in_sizes, int n_in,
                              void* d_out, int out_size, void* d_ws, size_t ws_size,
                              hipStream_t stream){
  const int*  y_t   = (const int*)d_in[0];
  const void* h0    = d_in[1];
  const void* c0    = d_in[2];
  const void* enc_outs  = d_in[3];
  const void* enc_feats = d_in[4];
  const void* mask  = d_in[5];
  const void* c_t_1 = d_in[6];
  // d_in[7] extra_zeros unused (zeros)
  const int*  ebev  = (const int*)d_in[8];
  const void* coverage = d_in[9];
  const void* embed_W = d_in[10];
  const void* Wih   = d_in[11];
  const void* Whh   = d_in[12];
  const void* bih   = d_in[13];
  const void* bhh   = d_in[14];
  const void* xctx_W = d_in[15];
  const void* xctx_b = d_in[16];
  const void* Ws_W  = d_in[17];
  const void* Ws_b  = d_in[18];
  const void* Wc_W  = d_in[19];
  const void* v_W   = d_in[20];
  const void* pgen_W = d_in[21];
  const void* pgen_b = d_in[22];
  const void* proj_W = d_in[23];
  const void* proj_b = d_in[24];
  const void* out_W = d_in[25];
  const void* out_b = d_in[26];

  // Workspace layout (float units). Total ~18.6 MB.
  float* ws        = (float*)d_ws;
  float* x_ws      = ws;                   // @0        16384
  float* st_ws     = ws + 16384;           //           65536
  float* dec_ws    = ws + 81920;           //           65536
  float* energy_ws = ws + 147456;          //           131072
  float* a_ws      = ws + 278528;          //           131072
  float* ct_ws     = ws + 409600;          //           65536
  float* pgen_ws   = ws + 475136;          //           128
  float* pm_ws     = ws + 475264;          //           512
  float* ps_ws     = ws + 475776;          //           512
  unsigned short* outhid_bf = (unsigned short*)(ws + 476576);  // 16384 floats (32768 bf16)
  unsigned short* logits_bf = (unsigned short*)(ws + 492960);  // 128*LSTR bf16 = 3207168 floats
  float* xctxT     = ws + 3700128;         //           81920
  float* gatesT    = ws + 3782048;         //           393216
  float* bg_ws     = ws + 4175264;         //           1024
  float* WsT       = ws + 4176288;         //           262144
  float* projT     = ws + 4438432;         //           196608  (end 4635040)

  k_pre  <<<1024, 256, 0, stream>>>(xctx_W, Wih, Whh, Ws_W, proj_W, bih, bhh, mask,
                                    xctxT, gatesT, bg_ws, WsT, projT);
  kA_row <<<128, 256, 0, stream>>>(y_t, c_t_1, embed_W, h0, c0, xctxT, xctx_b,
                                   gatesT, bg_ws, WsT, Ws_b, mask,
                                   x_ws, st_ws, dec_ws, d_out);
  k4_energy<<<1024, 256, 0, stream>>>(enc_feats, dec_ws, coverage, Wc_W, v_W, mask, energy_ws);
  k5_attn<<<128, 256, 0, stream>>>(energy_ws, mask, coverage, a_ws, ct_ws, d_out);
  k6_ctx <<<1024, 256, 0, stream>>>(a_ws, enc_outs, mask, ct_ws);
  kC_row <<<128, 256, 0, stream>>>(ct_ws, st_ws, x_ws, pgen_W, pgen_b, projT, proj_b,
                                   mask, pgen_ws, outhid_bf, d_out);
  k9_logits<<<(V_ / 16 + 3) / 4, 256, 0, stream>>>(outhid_bf, out_W, out_b, mask, logits_bf);
  k10_rowred<<<512, 256, 0, stream>>>(logits_bf, pm_ws, ps_ws);
  k11_vocab<<<dim3(25, 128), 256, 0, stream>>>(logits_bf, pm_ws, ps_ws, pgen_ws, mask, d_out);
  k12_scatter<<<512, 256, 0, stream>>>(ebev, a_ws, pgen_ws, mask, d_out);
}